// Round 13
// baseline (453.598 us; speedup 1.0000x reference)
//
#include <hip/hip_runtime.h>

typedef unsigned short u16;
typedef __attribute__((ext_vector_type(8))) __bf16 bf16x8;
typedef __attribute__((ext_vector_type(4))) float f32x4;

__device__ __forceinline__ float bf2f(u16 u) {
  union { unsigned int i; float f; } v; v.i = ((unsigned int)u) << 16; return v.f;
}
__device__ __forceinline__ u16 f2bf(float f) {
  union { float f; unsigned int i; } v; v.f = f;
  unsigned int u = v.i;
  return (u16)((u + 0x7fffu + ((u >> 16) & 1u)) >> 16);  // RNE
}
__device__ __forceinline__ void async16(void* lds, const void* g) {
  __builtin_amdgcn_global_load_lds(
      (const __attribute__((address_space(1))) unsigned int*)g,
      (__attribute__((address_space(3))) unsigned int*)lds, 16, 0, 0);
}

// ---------------- conversions ----------------
// 8 elems/thread, 16B stores
__global__ void k_convert_x(const float* __restrict__ x, u16* __restrict__ xb) {
  int idx = blockIdx.x * 256 + threadIdx.x;       // 65536*64 threads
  int m = idx >> 6, c0 = (idx & 63) * 8;
  u16 o[8];
#pragma unroll
  for (int j = 0; j < 8; ++j) {
    int c = c0 + j;
    o[j] = f2bf((c < 500) ? x[(size_t)m * 500 + c] : 0.f);
  }
  *(uint4*)(xb + (size_t)m * 512 + c0) = *(const uint4*)o;
}

// W^T, padded; for q,k the OUTPUT columns are permuted so RoPE pairs are
// adjacent: new col 2p <- old col p, new col 2p+1 <- old col p+250 (p<250).
__global__ void k_convert_w(const float* __restrict__ Wq, const float* __restrict__ Wk,
                            const float* __restrict__ Wv, u16* __restrict__ Wt) {
  int idx = blockIdx.x * 256 + threadIdx.x;       // 3*512*512
  int g = idx >> 18;
  int r = idx & 262143;
  int n = r >> 9, k = r & 511;
  const float* W = (g == 0) ? Wq : (g == 1) ? Wk : Wv;
  int orig = (g == 2) ? n : ((n & 1) ? (n >> 1) + 250 : (n >> 1));
  float v = (n < 500 && k < 500) ? W[(size_t)k * 500 + orig] : 0.f;
  Wt[idx] = f2bf(v);
}

// pair tables: cospair[t][p] = cos(t * freq_p), freq_p = 1e-4^(2*(p/2)/500)
__global__ void k_tables(float* __restrict__ cospair, float* __restrict__ sinpair) {
  int t = blockIdx.x, p = threadIdx.x;
  float c = 0.f, s = 0.f;
  if (p < 250) {
    float ex = (float)(2 * (p >> 1)) / 500.0f;
    float fr = powf(1e-4f, ex);
    float ang = (float)t * fr;
    c = cosf(ang); s = sinf(ang);
  }
  cospair[t * 256 + p] = c;
  sinpair[t * 256 + p] = s;
}

// ---------------- QKV projection GEMM + fused RoPE ----------------
// 512 M-rows x 64 N-cols per block, 4 waves (2x2). A via 4-slot LDS ring
// (64 KB), staged 2 tiles per barrier phase.
// NEW vs R12: B is DOUBLE-BUFFERED in registers (bA/bB, 8 frags = 32 VGPR
// each), prefetched one full phase ahead from L2 — R6..R12 plateaued at
// 22% MfmaUtil because VGPR=128 forced the allocator to rematerialize the
// full B panel from L2 inside every MFMA cluster (L2 latency on the
// critical path). Counted-vmcnt bookkeeping (FIFO retirement):
//   entry invariant: <=8 outstanding, newest 8 = this phase's B loads
//   STAGE x2 (8) | fence | BLOAD next (8) | vmcnt(16) -> entry B done
//   COMPUTE x2 | vmcnt(8) -> stages done, next B in flight | barrier
// The fence between STAGE and BLOAD is LOAD-BEARING: stages must be older
// than B loads so vmcnt(8) retires stages, not B.
// RESOURCE ENVELOPE: (256,2) only. (256,3)->cap 84 spills (R7, 3x);
// (512,4)->cap 64 spills (R10, 2.2x). Do not touch.
__global__ __launch_bounds__(256, 2) void k_gemm_qkv(
    const u16* __restrict__ xb, const u16* __restrict__ Wt,
    const float* __restrict__ cospair, const float* __restrict__ sinpair,
    u16* __restrict__ qb, u16* __restrict__ kb, u16* __restrict__ vT) {
  __shared__ u16 As[4][128][64];   // 64 KB
  const int tid = threadIdx.x;
  const int lane = tid & 63;
  const int w = tid >> 6;              // 0..3
  const int wm = w >> 1, wn = w & 1;   // 2x2 wave grid on 128M x 64N
  const int lrow = lane & 15, lhi = lane >> 4;
  const int sx = lrow & 7;

  int bid = blockIdx.x;
  int wk = (bid & 7) * 384 + (bid >> 3);
  int mg = wk / 24;
  int j24 = wk - mg * 24;
  int g = j24 >> 3, bni = j24 & 7;
  const int bn = bni << 6;             // 0..448 step 64
  const int m0 = mg << 9;              // 512 rows per block

  const u16* Ab = xb + (size_t)m0 * 512;
  const u16* Bl = Wt + ((size_t)(g * 512 + bn + wn * 32) + lrow) * 512 + lhi * 8;

  // two B pair-buffers: BUF[tile_half*4 + ni*2 + kk2], 8 frags each
  bf16x8 bA[8], bB[8];

  // stage tile S: A rows (S>>3)*128.., cols (S&7)*64..; ring slot S&3
#define STAGE(S) { int mt_ = (S) >> 3, t_ = (S) & 7, buf_ = (S) & 3;          \
    _Pragma("unroll")                                                         \
    for (int ld = 0; ld < 4; ++ld) {                                          \
      int gi = ld * 256 + tid;                                                \
      int r_ = gi >> 3, c_ = gi & 7;                                          \
      async16((char*)As + buf_ * 16384 + (size_t)gi * 16,                     \
              Ab + ((size_t)(mt_ * 128 + r_)) * 512 + t_ * 64 +               \
                  ((c_ ^ (r_ & 7)) * 8));                                     \
    } }

  // load B pair for steps C, C+1 into BUF (8 dwordx4 loads)
#define BLOAD(BUF, C) {                                                       \
    _Pragma("unroll")                                                         \
    for (int ni = 0; ni < 2; ++ni)                                            \
      _Pragma("unroll")                                                       \
      for (int kk2 = 0; kk2 < 2; ++kk2) {                                     \
        BUF[ni * 2 + kk2] =                                                   \
            *(const bf16x8*)(Bl + (size_t)ni * 16 * 512 + (C) * 64 + kk2 * 32);\
        BUF[4 + ni * 2 + kk2] =                                               \
            *(const bf16x8*)(Bl + (size_t)ni * 16 * 512 + ((C) + 1) * 64 + kk2 * 32);\
      } }

  // compute tile S using half H of BUF
#define COMPUTE(S, H, BUF) {                                                  \
    const u16* Asl = (const u16*)As + ((S) & 3) * 8192;                       \
    bf16x8 a[4][2];                                                           \
    _Pragma("unroll")                                                         \
    for (int mi = 0; mi < 4; ++mi)                                            \
      _Pragma("unroll")                                                       \
      for (int kk2 = 0; kk2 < 2; ++kk2)                                       \
        a[mi][kk2] = *(const bf16x8*)(Asl + (wm * 64 + mi * 16 + lrow) * 64 + \
                                      (((kk2 * 4 + lhi) ^ sx) * 8));          \
    __builtin_amdgcn_s_setprio(1);                                            \
    _Pragma("unroll")                                                         \
    for (int kk2 = 0; kk2 < 2; ++kk2)                                         \
      _Pragma("unroll")                                                       \
      for (int mi = 0; mi < 4; ++mi)                                          \
        _Pragma("unroll")                                                     \
        for (int ni = 0; ni < 2; ++ni)                                        \
          acc[mi][ni] = __builtin_amdgcn_mfma_f32_16x16x32_bf16(              \
              a[mi][kk2], BUF[(H) * 4 + ni * 2 + kk2], acc[mi][ni], 0, 0, 0); \
    __builtin_amdgcn_s_setprio(0);                                            \
  }

#define EPILOGUE(MT) {                                                        \
    int mb = m0 + (MT) * 128;                                                 \
    if (g < 2) {                                                              \
      u16* dst = (g == 0) ? qb : kb;                                          \
      _Pragma("unroll")                                                       \
      for (int mi = 0; mi < 4; ++mi)                                          \
        _Pragma("unroll")                                                     \
        for (int ni = 0; ni < 2; ++ni) {                                      \
          int n = bn + wn * 32 + ni * 16 + lrow;                              \
          int p = n >> 1;                                                     \
          _Pragma("unroll")                                                   \
          for (int jj = 0; jj < 4; ++jj) {                                    \
            int m = mb + wm * 64 + mi * 16 + lhi * 4 + jj;                    \
            float v = acc[mi][ni][jj];                                        \
            float o = __shfl_xor(v, 1, 64);                                   \
            int ti = (m & 255) * 256 + p;                                     \
            float c = cospair[ti], s = sinpair[ti];                           \
            float r = (n & 1) ? (o * s + v * c) : (v * c - o * s);            \
            dst[(size_t)m * 512 + n] = f2bf(r);                               \
          }                                                                   \
        }                                                                     \
    } else {                                                                  \
      _Pragma("unroll")                                                       \
      for (int mi = 0; mi < 4; ++mi)                                          \
        _Pragma("unroll")                                                     \
        for (int ni = 0; ni < 2; ++ni) {                                      \
          int n = bn + wn * 32 + ni * 16 + lrow;                              \
          _Pragma("unroll")                                                   \
          for (int jj = 0; jj < 4; ++jj) {                                    \
            int m = mb + wm * 64 + mi * 16 + lhi * 4 + jj;                    \
            vT[(size_t)(m >> 8) * 131072 + (size_t)n * 256 + (m & 255)] =     \
                f2bf(acc[mi][ni][jj]);                                        \
          }                                                                   \
        }                                                                     \
    } }

  // one barrier phase: tiles S,S+1 (B steps C,C+1 in CUR); prefetch
  // stages S+2,S+3 and B steps C+2,C+3 (mod 8) into NXT.
#define PHASE(S, C, CUR, NXT)                                                 \
    STAGE((S) + 2); STAGE((S) + 3);                                           \
    asm volatile("" ::: "memory");                                            \
    BLOAD(NXT, (((C) + 2) & 7));                                              \
    asm volatile("s_waitcnt vmcnt(16)" ::: "memory");                         \
    COMPUTE((S), 0, CUR); COMPUTE((S) + 1, 1, CUR);                           \
    asm volatile("s_waitcnt vmcnt(8)" ::: "memory");                          \
    __builtin_amdgcn_s_barrier();                                             \
    asm volatile("" ::: "memory");

  // prologue: stage tiles 0,1; load B steps 0,1 into bA
  STAGE(0); STAGE(1);
  asm volatile("" ::: "memory");
  BLOAD(bA, 0);
  asm volatile("s_waitcnt vmcnt(8)" ::: "memory");   // stages done, bA in flight
  __builtin_amdgcn_s_barrier();
  asm volatile("" ::: "memory");

#define MT_FULL(MT)                                                           \
  {                                                                           \
    f32x4 acc[4][2] = {};                                                     \
    PHASE((MT) * 8 + 0, 0, bA, bB)                                            \
    PHASE((MT) * 8 + 2, 2, bB, bA)                                            \
    PHASE((MT) * 8 + 4, 4, bA, bB)                                            \
    PHASE((MT) * 8 + 6, 6, bB, bA)                                            \
    EPILOGUE(MT);                                                             \
    asm volatile("s_waitcnt vmcnt(0)" ::: "memory");                          \
  }

  MT_FULL(0)
  MT_FULL(1)
  MT_FULL(2)
  {                                                  // mt = 3 (tail)
    f32x4 acc[4][2] = {};
    PHASE(24, 0, bA, bB)
    PHASE(26, 2, bB, bA)
    // phase (28,29): stage 30,31; load B steps 6,7 into bB
    STAGE(30); STAGE(31);
    asm volatile("" ::: "memory");
    BLOAD(bB, 6);
    asm volatile("s_waitcnt vmcnt(16)" ::: "memory");
    COMPUTE(28, 0, bA); COMPUTE(29, 1, bA);
    asm volatile("s_waitcnt vmcnt(8)" ::: "memory");
    __builtin_amdgcn_s_barrier();
    asm volatile("" ::: "memory");
    // final phase: tiles 30,31
    asm volatile("s_waitcnt vmcnt(0)" ::: "memory");
    COMPUTE(30, 0, bB); COMPUTE(31, 1, bB);
    EPILOGUE(3);
  }
#undef STAGE
#undef BLOAD
#undef COMPUTE
#undef EPILOGUE
#undef PHASE
#undef MT_FULL
}

// ---------------- fused causal attention, ring-pipelined ----------------
// block = (q-tile of 64 rows, batch), 4 waves x 16 rows.
// K tiles [16][512] (16KB) and V tiles [256h][32s] (16KB) stream through a
// 3-slot ring (48KB), distance-2 prefetch, counted vmcnt(4) — no drains in
// the main loops. P [64][256] bf16 at +48KB. Total 80KB -> 2 blocks/CU.
__global__ __launch_bounds__(256) void k_attn(
    const u16* __restrict__ qb, const u16* __restrict__ kb,
    const u16* __restrict__ vT, float* __restrict__ out) {
  __shared__ u16 smem[40960];          // 80 KB
  u16* Ring = smem;                    // 3 x 8192 u16 (16KB slots)
  u16* Ps = smem + 24576;              // [64][256]

  const int tid = threadIdx.x;
  const int lane = tid & 63;
  const int w = tid >> 6;
  int bid = blockIdx.x;                // 1024
  int wkk = (bid & 7) * 128 + (bid >> 3);
  const int b = wkk >> 2;
  const int qt = wkk & 3;
  const int t0 = qt * 64;
  const int lrow = lane & 15, lhi = lane >> 4;
  const int sx = lrow & 7;
  const int vxor = (lrow >> 1) & 3;
  const int NT = 4 * (qt + 1);         // K tiles (16 rows each), 4..16
  const int NTB = 2 * (qt + 1);        // V s-chunks (32 each), 2..8
  const int NV = 2 * NTB;              // V tiles (s-chunk x h-half), 4..16

  // Q fragments in registers
  const u16* qrow = qb + ((size_t)(b * 256 + t0 + w * 16 + lrow)) * 512;
  bf16x8 qf[16];
#pragma unroll
  for (int kk = 0; kk < 16; ++kk)
    qf[kk] = *(const bf16x8*)(qrow + kk * 32 + lhi * 8);

  // stage K tile ST (s-rows ST*16..+15) into ring slot ST%3, pre-swizzled
#define STAGE_K(ST) {                                                         \
    _Pragma("unroll")                                                         \
    for (int ld = 0; ld < 4; ++ld) {                                          \
      int gi = ld * 256 + tid;                                                \
      int r_ = gi >> 6, c_ = gi & 63;                                         \
      async16((char*)Ring + ((ST) % 3) * 16384 + (size_t)gi * 16,             \
              kb + ((size_t)(b * 256 + (ST) * 16 + r_)) * 512 +               \
                  ((c_ ^ (r_ & 7)) * 8));                                     \
    } }

  // stage V tile f=(ST,HH): h-rows HH*256..+255, s-cols ST*32..+31
#define STAGE_V(ST, HH) {                                                     \
    _Pragma("unroll")                                                         \
    for (int ld = 0; ld < 4; ++ld) {                                          \
      int gi = ld * 256 + tid;                                                \
      int r_ = gi >> 2, c_ = gi & 3;                                          \
      async16((char*)Ring + (((ST) * 2 + (HH)) % 3) * 16384 + (size_t)gi * 16,\
              vT + (size_t)b * 131072 + ((size_t)((HH) * 256 + r_)) * 256 +   \
                  (ST) * 32 + ((c_ ^ ((r_ >> 1) & 3)) * 8));                  \
    } }

  // ---- phase A: S = Q K^T, ring-pipelined over NT 16-row K tiles ----
  f32x4 sa[16] = {};
  STAGE_K(0); STAGE_K(1);
  asm volatile("s_waitcnt vmcnt(4)" ::: "memory");
  __builtin_amdgcn_s_barrier();
  asm volatile("" ::: "memory");
#pragma unroll
  for (int st = 0; st < 16; ++st) {
    if (st < NT) {
      if (st + 2 < NT) STAGE_K(st + 2);
      const u16* Ksl = Ring + (st % 3) * 8192 + lrow * 512;
      __builtin_amdgcn_s_setprio(1);
#pragma unroll
      for (int kk = 0; kk < 16; ++kk) {
        bf16x8 bf = *(const bf16x8*)(Ksl + ((kk * 4 + lhi) ^ sx) * 8);
        sa[st] = __builtin_amdgcn_mfma_f32_16x16x32_bf16(qf[kk], bf, sa[st], 0, 0, 0);
      }
      __builtin_amdgcn_s_setprio(0);
      if (st + 2 < NT)      asm volatile("s_waitcnt vmcnt(4)" ::: "memory");
      else if (st + 1 < NT) asm volatile("s_waitcnt vmcnt(0)" ::: "memory");
      if (st + 1 < NT) {
        __builtin_amdgcn_s_barrier();
        asm volatile("" ::: "memory");
      }
    }
  }

  // ---- softmax (rows spread over 16 lrow lanes) ----
  const float scale = 0.04472135954999579f;   // 500^-0.5
  float rmax[4] = {-1e30f, -1e30f, -1e30f, -1e30f};
#pragma unroll
  for (int n = 0; n < 16; ++n) {
    int s = n * 16 + lrow;
#pragma unroll
    for (int j = 0; j < 4; ++j) {
      int t = t0 + w * 16 + lhi * 4 + j;
      float v = sa[n][j] * scale;
      if (s > t) v = -1e30f;
      sa[n][j] = v;
      rmax[j] = fmaxf(rmax[j], v);
    }
  }
#pragma unroll
  for (int j = 0; j < 4; ++j)
#pragma unroll
    for (int msk = 1; msk < 16; msk <<= 1)
      rmax[j] = fmaxf(rmax[j], __shfl_xor(rmax[j], msk, 64));
  float rsum[4] = {0.f, 0.f, 0.f, 0.f};
#pragma unroll
  for (int n = 0; n < 16; ++n)
#pragma unroll
    for (int j = 0; j < 4; ++j) {
      float p = __expf(sa[n][j] - rmax[j]);
      sa[n][j] = p;
      rsum[j] += p;
    }
#pragma unroll
  for (int j = 0; j < 4; ++j)
#pragma unroll
    for (int msk = 1; msk < 16; msk <<= 1)
      rsum[j] += __shfl_xor(rsum[j], msk, 64);
  float rinv[4];
#pragma unroll
  for (int j = 0; j < 4; ++j) rinv[j] = 1.0f / rsum[j];

  // write P (bf16) to LDS, 16B-slot swizzled
#pragma unroll
  for (int n = 0; n < 16; ++n)
#pragma unroll
    for (int j = 0; j < 4; ++j) {
      int s = n * 16 + lrow;
      int trow = w * 16 + lhi * 4 + j;
      int slot = (s >> 3) ^ (trow & 7);
      Ps[trow * 256 + slot * 8 + (s & 7)] = f2bf(sa[n][j] * rinv[j]);
    }

  // realias barrier: all K reads done + P visible before V staging
  __syncthreads();

  // ---- phase B: O = P V, ring-pipelined over NV (s-chunk, h-half) tiles --
  f32x4 o[2][16] = {};
  STAGE_V(0, 0); STAGE_V(0, 1);
  asm volatile("s_waitcnt vmcnt(4)" ::: "memory");
  __builtin_amdgcn_s_barrier();
  asm volatile("" ::: "memory");
#pragma unroll
  for (int st = 0; st < 8; ++st) {
    if (st < NTB) {
#pragma unroll
      for (int hh = 0; hh < 2; ++hh) {
        const int f = st * 2 + hh;
        if (f + 2 < NV) {
          if (hh == 0) STAGE_V(st + 1, 0) else STAGE_V(st + 1, 1);
        }
        bf16x8 pf = *(const bf16x8*)&Ps[(w * 16 + lrow) * 256 + ((st * 4 + lhi) ^ sx) * 8];
        const u16* Vsl = Ring + (f % 3) * 8192;
        __builtin_amdgcn_s_setprio(1);
#pragma unroll
        for (int ni = 0; ni < 16; ++ni) {
          bf16x8 vf = *(const bf16x8*)(Vsl + (ni * 16 + lrow) * 32 + (lhi ^ vxor) * 8);
          o[hh][ni] = __builtin_amdgcn_mfma_f32_16x16x32_bf16(pf, vf, o[hh][ni], 0, 0, 0);
        }
        __builtin_amdgcn_s_setprio(0);
        if (f + 2 < NV)      asm volatile("s_waitcnt vmcnt(4)" ::: "memory");
        else if (f + 1 < NV) asm volatile("s_waitcnt vmcnt(0)" ::: "memory");
        if (f + 1 < NV) {
          __builtin_amdgcn_s_barrier();
          asm volatile("" ::: "memory");
        }
      }
    }
  }
#undef STAGE_K
#undef STAGE_V

  // ---- epilogue ----
  const int tb = t0 + w * 16;
#pragma unroll
  for (int hh = 0; hh < 2; ++hh)
#pragma unroll
    for (int ni = 0; ni < 16; ++ni) {
      int h = hh * 256 + ni * 16 + lrow;
      if (h < 500) {
#pragma unroll
        for (int j = 0; j < 4; ++j) {
          int t = tb + lhi * 4 + j;
          out[((size_t)(b * 256 + t)) * 500 + h] = o[hh][ni][j];
        }
      }
    }
}

extern "C" void kernel_launch(void* const* d_in, const int* in_sizes, int n_in,
                              void* d_out, int out_size, void* d_ws, size_t ws_size,
                              hipStream_t stream) {
  const float* x  = (const float*)d_in[0];
  const float* Wq = (const float*)d_in[1];
  const float* Wk = (const float*)d_in[2];
  const float* Wv = (const float*)d_in[3];
  float* out = (float*)d_out;

  u16* xb = (u16*)d_ws;                 // [65536][512] bf16
  u16* qb = xb + 33554432;              // [65536][512]
  u16* kb = qb + 33554432;              // [65536][512]
  u16* vT = kb + 33554432;              // [256][512][256]
  u16* Wt = vT + 33554432;              // [1536][512]
  float* cospair = (float*)(Wt + 786432); // [256][256]
  float* sinpair = cospair + 65536;       // [256][256]

  k_convert_x<<<16384, 256, 0, stream>>>(x, xb);
  k_convert_w<<<3072, 256, 0, stream>>>(Wq, Wk, Wv, Wt);
  k_tables<<<256, 256, 0, stream>>>(cospair, sinpair);
  k_gemm_qkv<<<3072, 256, 0, stream>>>(xb, Wt, cospair, sinpair, qb, kb, vT);
  k_attn<<<1024, 256, 0, stream>>>(qb, kb, vT, out);
}

// Round 14
// 329.530 us; speedup vs baseline: 1.3765x; 1.3765x over previous
//
#include <hip/hip_runtime.h>

typedef unsigned short u16;
typedef __attribute__((ext_vector_type(8))) __bf16 bf16x8;
typedef __attribute__((ext_vector_type(4))) float f32x4;

__device__ __forceinline__ float bf2f(u16 u) {
  union { unsigned int i; float f; } v; v.i = ((unsigned int)u) << 16; return v.f;
}
__device__ __forceinline__ u16 f2bf(float f) {
  union { float f; unsigned int i; } v; v.f = f;
  unsigned int u = v.i;
  return (u16)((u + 0x7fffu + ((u >> 16) & 1u)) >> 16);  // RNE
}
__device__ __forceinline__ void async16(void* lds, const void* g) {
  __builtin_amdgcn_global_load_lds(
      (const __attribute__((address_space(1))) unsigned int*)g,
      (__attribute__((address_space(3))) unsigned int*)lds, 16, 0, 0);
}

// ---------------- conversions ----------------
// 8 elems/thread; float4 loads (row base m*2000B is 16B-aligned; c0*4 is
// 32B-aligned), 16B stores. Tail c0>=496 scalar.
__global__ void k_convert_x(const float* __restrict__ x, u16* __restrict__ xb) {
  int idx = blockIdx.x * 256 + threadIdx.x;       // 65536*64 threads
  int m = idx >> 6, c0 = (idx & 63) * 8;
  u16 o[8];
  if (c0 < 496) {
    float4 v0 = *(const float4*)(x + (size_t)m * 500 + c0);
    float4 v1 = *(const float4*)(x + (size_t)m * 500 + c0 + 4);
    o[0] = f2bf(v0.x); o[1] = f2bf(v0.y); o[2] = f2bf(v0.z); o[3] = f2bf(v0.w);
    o[4] = f2bf(v1.x); o[5] = f2bf(v1.y); o[6] = f2bf(v1.z); o[7] = f2bf(v1.w);
  } else {
#pragma unroll
    for (int j = 0; j < 8; ++j) {
      int c = c0 + j;
      o[j] = f2bf((c < 500) ? x[(size_t)m * 500 + c] : 0.f);
    }
  }
  *(uint4*)(xb + (size_t)m * 512 + c0) = *(const uint4*)o;
}

// W^T, padded; for q,k the OUTPUT columns are permuted so RoPE pairs are
// adjacent: new col 2p <- old col p, new col 2p+1 <- old col p+250 (p<250).
__global__ void k_convert_w(const float* __restrict__ Wq, const float* __restrict__ Wk,
                            const float* __restrict__ Wv, u16* __restrict__ Wt) {
  int idx = blockIdx.x * 256 + threadIdx.x;       // 3*512*512
  int g = idx >> 18;
  int r = idx & 262143;
  int n = r >> 9, k = r & 511;
  const float* W = (g == 0) ? Wq : (g == 1) ? Wk : Wv;
  int orig = (g == 2) ? n : ((n & 1) ? (n >> 1) + 250 : (n >> 1));
  float v = (n < 500 && k < 500) ? W[(size_t)k * 500 + orig] : 0.f;
  Wt[idx] = f2bf(v);
}

// pair tables: cospair[t][p] = cos(t * freq_p), freq_p = 1e-4^(2*(p/2)/500)
__global__ void k_tables(float* __restrict__ cospair, float* __restrict__ sinpair) {
  int t = blockIdx.x, p = threadIdx.x;
  float c = 0.f, s = 0.f;
  if (p < 250) {
    float ex = (float)(2 * (p >> 1)) / 500.0f;
    float fr = powf(1e-4f, ex);
    float ang = (float)t * fr;
    c = cosf(ang); s = sinf(ang);
  }
  cospair[t * 256 + p] = c;
  sinpair[t * 256 + p] = s;
}

// ---------------- QKV projection GEMM + fused RoPE (8-wave) ----------------
// Block: 512 threads = 8 waves (2M x 4N) on 128M x 128N per M-tile; 4
// M-tiles (512 rows). Wave tile 64x32, B-slice in registers/remat from L2.
// A via 4-slot LDS ring (64 KB) shared by all 8 waves, distance-3, counted
// vmcnt(4)/(2)/(0). Same staging bytes as the 4-wave version but 2x MFMA
// per step and 2x TLP (4 waves/SIMD at 2 blocks/CU).
// LAUNCH BOUNDS: cap ~= 256/arg2. (512,2) -> 128 VGPR (= what the 4-wave
// version uses; fits). (512,4) -> 64 -> B spills (R10: 2.2x regression).
// (256,3) -> 84 -> spills (R7: 3x). Do not change arg2.
__global__ __launch_bounds__(512, 2) void k_gemm_qkv(
    const u16* __restrict__ xb, const u16* __restrict__ Wt,
    const float* __restrict__ cospair, const float* __restrict__ sinpair,
    u16* __restrict__ qb, u16* __restrict__ kb, u16* __restrict__ vT) {
  __shared__ u16 As[4][128][64];   // 64 KB
  const int tid = threadIdx.x;
  const int lane = tid & 63;
  const int w = tid >> 6;              // 0..7
  const int wm = w >> 2, wn = w & 3;   // 2M x 4N wave grid on 128M x 128N
  const int lrow = lane & 15, lhi = lane >> 4;
  const int sx = lrow & 7;

  // XCD-chunked bijective swizzle: 1536 blocks, 192/XCD;
  // the 12 (g,bn) variants of one m-group adjacent (share A-panel in L2).
  int bid = blockIdx.x;
  int wk = (bid & 7) * 192 + (bid >> 3);
  int mg = wk / 12;
  int j12 = wk - mg * 12;
  int g = j12 >> 2, bni = j12 & 3;
  const int bn = bni << 7;             // 0,128,256,384
  const int m0 = mg << 9;              // 512 rows per block

  const u16* Ab = xb + (size_t)m0 * 512;

  // ---- B slice in registers (once, from L2): 32 cols per wave ----
  bf16x8 breg[8][2][2];
  {
    const u16* Bl = Wt + ((size_t)(g * 512 + bn + wn * 32) + lrow) * 512 + lhi * 8;
#pragma unroll
    for (int t = 0; t < 8; ++t)
#pragma unroll
      for (int ni = 0; ni < 2; ++ni)
#pragma unroll
        for (int kk2 = 0; kk2 < 2; ++kk2)
          breg[t][ni][kk2] =
              *(const bf16x8*)(Bl + (size_t)ni * 16 * 512 + t * 64 + kk2 * 32);
  }

  // stage step S (S = mt*8 + t): A rows m0+mt*128.., cols t*64..; slot S&3
  // 512 threads -> 2 loads/thread/step
#define STAGE(S) { int mt_ = (S) >> 3, t_ = (S) & 7, buf_ = (S) & 3;          \
    _Pragma("unroll")                                                         \
    for (int ld = 0; ld < 2; ++ld) {                                          \
      int gi = ld * 512 + tid;                                                \
      int r_ = gi >> 3, c_ = gi & 7;                                          \
      async16((char*)As + buf_ * 16384 + (size_t)gi * 16,                     \
              Ab + ((size_t)(mt_ * 128 + r_)) * 512 + t_ * 64 +               \
                  ((c_ ^ (r_ & 7)) * 8));                                     \
    } }

#define AFRAGS(S)                                                             \
    const u16* Asl = (const u16*)As + ((S) & 3) * 8192;                       \
    bf16x8 a[4][2];                                                           \
    _Pragma("unroll")                                                         \
    for (int mi = 0; mi < 4; ++mi)                                            \
      _Pragma("unroll")                                                       \
      for (int kk2 = 0; kk2 < 2; ++kk2)                                       \
        a[mi][kk2] = *(const bf16x8*)(Asl + (wm * 64 + mi * 16 + lrow) * 64 + \
                                      (((kk2 * 4 + lhi) ^ sx) * 8));

#define EPILOGUE(MT) {                                                        \
    int mb = m0 + (MT) * 128;                                                 \
    if (g < 2) {                                                              \
      u16* dst = (g == 0) ? qb : kb;                                          \
      _Pragma("unroll")                                                       \
      for (int mi = 0; mi < 4; ++mi)                                          \
        _Pragma("unroll")                                                     \
        for (int ni = 0; ni < 2; ++ni) {                                      \
          int n = bn + wn * 32 + ni * 16 + lrow;                              \
          int p = n >> 1;                                                     \
          _Pragma("unroll")                                                   \
          for (int jj = 0; jj < 4; ++jj) {                                    \
            int m = mb + wm * 64 + mi * 16 + lhi * 4 + jj;                    \
            float v = acc[mi][ni][jj];                                        \
            float o = __shfl_xor(v, 1, 64);                                   \
            int ti = (m & 255) * 256 + p;                                     \
            float c = cospair[ti], s = sinpair[ti];                           \
            float r = (n & 1) ? (o * s + v * c) : (v * c - o * s);            \
            dst[(size_t)m * 512 + n] = f2bf(r);                               \
          }                                                                   \
        }                                                                     \
    } else {                                                                  \
      _Pragma("unroll")                                                       \
      for (int mi = 0; mi < 4; ++mi)                                          \
        _Pragma("unroll")                                                     \
        for (int ni = 0; ni < 2; ++ni) {                                      \
          int n = bn + wn * 32 + ni * 16 + lrow;                              \
          _Pragma("unroll")                                                   \
          for (int jj = 0; jj < 4; ++jj) {                                    \
            int m = mb + wm * 64 + mi * 16 + lhi * 4 + jj;                    \
            vT[(size_t)(m >> 8) * 131072 + (size_t)n * 256 + (m & 255)] =     \
                f2bf(acc[mi][ni][jj]);                                        \
          }                                                                   \
        }                                                                     \
    } }

  STAGE(0); STAGE(1); STAGE(2);
  asm volatile("s_waitcnt vmcnt(4)" ::: "memory");   // tile 0 resident
  __builtin_amdgcn_s_barrier();
  asm volatile("" ::: "memory");

  for (int mt = 0; mt < 3; ++mt) {
    f32x4 acc[4][2] = {};
#pragma unroll
    for (int t = 0; t < 8; ++t) {
      STAGE(mt * 8 + t + 3);
      AFRAGS(t);
      __builtin_amdgcn_s_setprio(1);
#pragma unroll
      for (int kk2 = 0; kk2 < 2; ++kk2)
#pragma unroll
        for (int mi = 0; mi < 4; ++mi)
#pragma unroll
          for (int ni = 0; ni < 2; ++ni)
            acc[mi][ni] = __builtin_amdgcn_mfma_f32_16x16x32_bf16(
                a[mi][kk2], breg[t][ni][kk2], acc[mi][ni], 0, 0, 0);
      __builtin_amdgcn_s_setprio(0);
      asm volatile("s_waitcnt vmcnt(4)" ::: "memory");
      __builtin_amdgcn_s_barrier();
      asm volatile("" ::: "memory");
    }
    EPILOGUE(mt);
  }
  {                                                  // mt = 3 (tail)
    f32x4 acc[4][2] = {};
#pragma unroll
    for (int t = 0; t < 8; ++t) {
      if (t < 5) STAGE(27 + t);
      AFRAGS(t);
      __builtin_amdgcn_s_setprio(1);
#pragma unroll
      for (int kk2 = 0; kk2 < 2; ++kk2)
#pragma unroll
        for (int mi = 0; mi < 4; ++mi)
#pragma unroll
          for (int ni = 0; ni < 2; ++ni)
            acc[mi][ni] = __builtin_amdgcn_mfma_f32_16x16x32_bf16(
                a[mi][kk2], breg[t][ni][kk2], acc[mi][ni], 0, 0, 0);
      __builtin_amdgcn_s_setprio(0);
      if (t < 5)       asm volatile("s_waitcnt vmcnt(4)" ::: "memory");
      else if (t == 5) asm volatile("s_waitcnt vmcnt(2)" ::: "memory");
      else if (t == 6) asm volatile("s_waitcnt vmcnt(0)" ::: "memory");
      if (t < 7) {
        __builtin_amdgcn_s_barrier();
        asm volatile("" ::: "memory");
      }
    }
    EPILOGUE(3);
  }
#undef STAGE
#undef AFRAGS
#undef EPILOGUE
}

// ---------------- fused causal attention, ring-pipelined ----------------
// block = (q-tile of 64 rows, batch), 4 waves x 16 rows.
// K tiles [16][512] (16KB) and V tiles [256h][32s] (16KB) stream through a
// 3-slot ring (48KB), distance-2 prefetch, counted vmcnt(4) — no drains in
// the main loops. P [64][256] bf16 at +48KB. Total 80KB -> 2 blocks/CU.
__global__ __launch_bounds__(256) void k_attn(
    const u16* __restrict__ qb, const u16* __restrict__ kb,
    const u16* __restrict__ vT, float* __restrict__ out) {
  __shared__ u16 smem[40960];          // 80 KB
  u16* Ring = smem;                    // 3 x 8192 u16 (16KB slots)
  u16* Ps = smem + 24576;              // [64][256]

  const int tid = threadIdx.x;
  const int lane = tid & 63;
  const int w = tid >> 6;
  int bid = blockIdx.x;                // 1024
  int wkk = (bid & 7) * 128 + (bid >> 3);
  const int b = wkk >> 2;
  const int qt = wkk & 3;
  const int t0 = qt * 64;
  const int lrow = lane & 15, lhi = lane >> 4;
  const int sx = lrow & 7;
  const int vxor = (lrow >> 1) & 3;
  const int NT = 4 * (qt + 1);         // K tiles (16 rows each), 4..16
  const int NTB = 2 * (qt + 1);        // V s-chunks (32 each), 2..8
  const int NV = 2 * NTB;              // V tiles (s-chunk x h-half), 4..16

  // Q fragments in registers
  const u16* qrow = qb + ((size_t)(b * 256 + t0 + w * 16 + lrow)) * 512;
  bf16x8 qf[16];
#pragma unroll
  for (int kk = 0; kk < 16; ++kk)
    qf[kk] = *(const bf16x8*)(qrow + kk * 32 + lhi * 8);

  // stage K tile ST (s-rows ST*16..+15) into ring slot ST%3, pre-swizzled
#define STAGE_K(ST) {                                                         \
    _Pragma("unroll")                                                         \
    for (int ld = 0; ld < 4; ++ld) {                                          \
      int gi = ld * 256 + tid;                                                \
      int r_ = gi >> 6, c_ = gi & 63;                                         \
      async16((char*)Ring + ((ST) % 3) * 16384 + (size_t)gi * 16,             \
              kb + ((size_t)(b * 256 + (ST) * 16 + r_)) * 512 +               \
                  ((c_ ^ (r_ & 7)) * 8));                                     \
    } }

  // stage V tile f=(ST,HH): h-rows HH*256..+255, s-cols ST*32..+31
#define STAGE_V(ST, HH) {                                                     \
    _Pragma("unroll")                                                         \
    for (int ld = 0; ld < 4; ++ld) {                                          \
      int gi = ld * 256 + tid;                                                \
      int r_ = gi >> 2, c_ = gi & 3;                                          \
      async16((char*)Ring + (((ST) * 2 + (HH)) % 3) * 16384 + (size_t)gi * 16,\
              vT + (size_t)b * 131072 + ((size_t)((HH) * 256 + r_)) * 256 +   \
                  (ST) * 32 + ((c_ ^ ((r_ >> 1) & 3)) * 8));                  \
    } }

  // ---- phase A: S = Q K^T, ring-pipelined over NT 16-row K tiles ----
  f32x4 sa[16] = {};
  STAGE_K(0); STAGE_K(1);
  asm volatile("s_waitcnt vmcnt(4)" ::: "memory");
  __builtin_amdgcn_s_barrier();
  asm volatile("" ::: "memory");
#pragma unroll
  for (int st = 0; st < 16; ++st) {
    if (st < NT) {
      if (st + 2 < NT) STAGE_K(st + 2);
      const u16* Ksl = Ring + (st % 3) * 8192 + lrow * 512;
      __builtin_amdgcn_s_setprio(1);
#pragma unroll
      for (int kk = 0; kk < 16; ++kk) {
        bf16x8 bf = *(const bf16x8*)(Ksl + ((kk * 4 + lhi) ^ sx) * 8);
        sa[st] = __builtin_amdgcn_mfma_f32_16x16x32_bf16(qf[kk], bf, sa[st], 0, 0, 0);
      }
      __builtin_amdgcn_s_setprio(0);
      if (st + 2 < NT)      asm volatile("s_waitcnt vmcnt(4)" ::: "memory");
      else if (st + 1 < NT) asm volatile("s_waitcnt vmcnt(0)" ::: "memory");
      if (st + 1 < NT) {
        __builtin_amdgcn_s_barrier();
        asm volatile("" ::: "memory");
      }
    }
  }

  // ---- softmax (rows spread over 16 lrow lanes) ----
  const float scale = 0.04472135954999579f;   // 500^-0.5
  float rmax[4] = {-1e30f, -1e30f, -1e30f, -1e30f};
#pragma unroll
  for (int n = 0; n < 16; ++n) {
    int s = n * 16 + lrow;
#pragma unroll
    for (int j = 0; j < 4; ++j) {
      int t = t0 + w * 16 + lhi * 4 + j;
      float v = sa[n][j] * scale;
      if (s > t) v = -1e30f;
      sa[n][j] = v;
      rmax[j] = fmaxf(rmax[j], v);
    }
  }
#pragma unroll
  for (int j = 0; j < 4; ++j)
#pragma unroll
    for (int msk = 1; msk < 16; msk <<= 1)
      rmax[j] = fmaxf(rmax[j], __shfl_xor(rmax[j], msk, 64));
  float rsum[4] = {0.f, 0.f, 0.f, 0.f};
#pragma unroll
  for (int n = 0; n < 16; ++n)
#pragma unroll
    for (int j = 0; j < 4; ++j) {
      float p = __expf(sa[n][j] - rmax[j]);
      sa[n][j] = p;
      rsum[j] += p;
    }
#pragma unroll
  for (int j = 0; j < 4; ++j)
#pragma unroll
    for (int msk = 1; msk < 16; msk <<= 1)
      rsum[j] += __shfl_xor(rsum[j], msk, 64);
  float rinv[4];
#pragma unroll
  for (int j = 0; j < 4; ++j) rinv[j] = 1.0f / rsum[j];

  // write P (bf16) to LDS, 16B-slot swizzled
#pragma unroll
  for (int n = 0; n < 16; ++n)
#pragma unroll
    for (int j = 0; j < 4; ++j) {
      int s = n * 16 + lrow;
      int trow = w * 16 + lhi * 4 + j;
      int slot = (s >> 3) ^ (trow & 7);
      Ps[trow * 256 + slot * 8 + (s & 7)] = f2bf(sa[n][j] * rinv[j]);
    }

  // realias barrier: all K reads done + P visible before V staging
  __syncthreads();

  // ---- phase B: O = P V, ring-pipelined over NV (s-chunk, h-half) tiles --
  f32x4 o[2][16] = {};
  STAGE_V(0, 0); STAGE_V(0, 1);
  asm volatile("s_waitcnt vmcnt(4)" ::: "memory");
  __builtin_amdgcn_s_barrier();
  asm volatile("" ::: "memory");
#pragma unroll
  for (int st = 0; st < 8; ++st) {
    if (st < NTB) {
#pragma unroll
      for (int hh = 0; hh < 2; ++hh) {
        const int f = st * 2 + hh;
        if (f + 2 < NV) {
          if (hh == 0) STAGE_V(st + 1, 0) else STAGE_V(st + 1, 1);
        }
        bf16x8 pf = *(const bf16x8*)&Ps[(w * 16 + lrow) * 256 + ((st * 4 + lhi) ^ sx) * 8];
        const u16* Vsl = Ring + (f % 3) * 8192;
        __builtin_amdgcn_s_setprio(1);
#pragma unroll
        for (int ni = 0; ni < 16; ++ni) {
          bf16x8 vf = *(const bf16x8*)(Vsl + (ni * 16 + lrow) * 32 + (lhi ^ vxor) * 8);
          o[hh][ni] = __builtin_amdgcn_mfma_f32_16x16x32_bf16(pf, vf, o[hh][ni], 0, 0, 0);
        }
        __builtin_amdgcn_s_setprio(0);
        if (f + 2 < NV)      asm volatile("s_waitcnt vmcnt(4)" ::: "memory");
        else if (f + 1 < NV) asm volatile("s_waitcnt vmcnt(0)" ::: "memory");
        if (f + 1 < NV) {
          __builtin_amdgcn_s_barrier();
          asm volatile("" ::: "memory");
        }
      }
    }
  }
#undef STAGE_K
#undef STAGE_V

  // ---- epilogue ----
  const int tb = t0 + w * 16;
#pragma unroll
  for (int hh = 0; hh < 2; ++hh)
#pragma unroll
    for (int ni = 0; ni < 16; ++ni) {
      int h = hh * 256 + ni * 16 + lrow;
      if (h < 500) {
#pragma unroll
        for (int j = 0; j < 4; ++j) {
          int t = tb + lhi * 4 + j;
          out[((size_t)(b * 256 + t)) * 500 + h] = o[hh][ni][j];
        }
      }
    }
}

extern "C" void kernel_launch(void* const* d_in, const int* in_sizes, int n_in,
                              void* d_out, int out_size, void* d_ws, size_t ws_size,
                              hipStream_t stream) {
  const float* x  = (const float*)d_in[0];
  const float* Wq = (const float*)d_in[1];
  const float* Wk = (const float*)d_in[2];
  const float* Wv = (const float*)d_in[3];
  float* out = (float*)d_out;

  u16* xb = (u16*)d_ws;                 // [65536][512] bf16
  u16* qb = xb + 33554432;              // [65536][512]
  u16* kb = qb + 33554432;              // [65536][512]
  u16* vT = kb + 33554432;              // [256][512][256]
  u16* Wt = vT + 33554432;              // [1536][512]
  float* cospair = (float*)(Wt + 786432); // [256][256]
  float* sinpair = cospair + 65536;       // [256][256]

  k_convert_x<<<16384, 256, 0, stream>>>(x, xb);
  k_convert_w<<<3072, 256, 0, stream>>>(Wq, Wk, Wv, Wt);
  k_tables<<<256, 256, 0, stream>>>(cospair, sinpair);
  k_gemm_qkv<<<1536, 512, 0, stream>>>(xb, Wt, cospair, sinpair, qb, kb, vT);
  k_attn<<<1024, 256, 0, stream>>>(qb, kb, vT, out);
}